// Round 17
// baseline (208.565 us; speedup 1.0000x reference)
//
#include <hip/hip_runtime.h>

typedef _Float16 v2h __attribute__((ext_vector_type(2)));

#define BB 128
#define TT 512
#define NN 200
#define START_IDX 1
#define END_IDX 2

#define NT 256        // 4 waves
#define QI 28         // valid halves per chunk (chunk owner c = lane&7)
#define CH 40         // padded halves per chunk: 80B stride, conflict-free banks
#define PSLOTS (8*CH) // 320

__device__ __forceinline__ float fdot2(v2h a, v2h b, float c) {
  return __builtin_amdgcn_fdot2(a, b, c, false);
}

// LDS-only barrier: does NOT drain vmcnt (global u-prefetch stays in flight).
__device__ __forceinline__ void sync_lds() {
  asm volatile("s_waitcnt lgkmcnt(0)" ::: "memory");
  __builtin_amdgcn_s_barrier();
}

// sum over 8 consecutive lanes; all 8 lanes get the sum
__device__ __forceinline__ float dpp_add8(float x) {
  int v;
  v = __builtin_amdgcn_mov_dpp(__float_as_int(x), 0xB1, 0xF, 0xF, true);
  x += __int_as_float(v);
  v = __builtin_amdgcn_mov_dpp(__float_as_int(x), 0x4E, 0xF, 0xF, true);
  x += __int_as_float(v);
  v = __builtin_amdgcn_mov_dpp(__float_as_int(x), 0x141, 0xF, 0xF, true);
  x += __int_as_float(v);
  return x;
}

// max over 8 consecutive lanes; all 8 lanes get the max
__device__ __forceinline__ float dpp_max8(float x) {
  int v;
  v = __builtin_amdgcn_mov_dpp(__float_as_int(x), 0xB1, 0xF, 0xF, true);
  x = fmaxf(x, __int_as_float(v));
  v = __builtin_amdgcn_mov_dpp(__float_as_int(x), 0x4E, 0xF, 0xF, true);
  x = fmaxf(x, __int_as_float(v));
  v = __builtin_amdgcn_mov_dpp(__float_as_int(x), 0x141, 0xF, 0xF, true);
  x = fmaxf(x, __int_as_float(v));
  return x;
}

// full-wave max (nonneg inputs), pure DPP; result valid in lane 63
__device__ __forceinline__ float wave_max_dpp(float x) {
  int v;
  v = __builtin_amdgcn_mov_dpp(__float_as_int(x), 0xB1, 0xF, 0xF, true);
  x = fmaxf(x, __int_as_float(v));
  v = __builtin_amdgcn_mov_dpp(__float_as_int(x), 0x4E, 0xF, 0xF, true);
  x = fmaxf(x, __int_as_float(v));
  v = __builtin_amdgcn_mov_dpp(__float_as_int(x), 0x141, 0xF, 0xF, true);
  x = fmaxf(x, __int_as_float(v));
  v = __builtin_amdgcn_mov_dpp(__float_as_int(x), 0x140, 0xF, 0xF, true);
  x = fmaxf(x, __int_as_float(v));
  v = __builtin_amdgcn_mov_dpp(__float_as_int(x), 0x142, 0xF, 0xF, true);
  x = fmaxf(x, __int_as_float(v));
  v = __builtin_amdgcn_mov_dpp(__float_as_int(x), 0x143, 0xF, 0xF, true);
  x = fmaxf(x, __int_as_float(v));
  return x;
}

// One block = one half-chain. Block 2b = forward half of chain b (computes
// a_h = M_{h-1}..M_0 a0, h = len/2 steps); block 2b+1 = backward half
// (computes c_h = M_h^T..M_{len-1}^T r, len-h steps, using E^T).
// Z_b = c_h . a_h, merged in crf_merge_kernel.
__global__ __attribute__((amdgpu_flat_work_group_size(NT, NT),
                          amdgpu_waves_per_eu(1, 1)))
void crf_half_kernel(
    const float* __restrict__ unary, const int* __restrict__ tags,
    const int* __restrict__ lengths, const float* __restrict__ trans,
    float* __restrict__ ws) {
  const int bx = blockIdx.x;
  const int b = bx >> 1;
  const bool isF = (bx & 1) == 0;
  const int tid = threadIdx.x;
  const int lane = tid & 63;
  const int wave = tid >> 6;       // 0..3
  const int c = lane & 7;          // i-chunk: i in [28c, 28c+28)
  const int g = (lane >> 3) & 7;   // group within wave
  const int gg = (wave << 3) + g;  // global group id, 0..31
  const int len = lengths[b];
  const int h = len >> 1;
  const int nsteps = isF ? h : (len - h);

  // double-buffered fp16 vector, 80B chunk stride. Pad halves 28..29 of chunk
  // w carry (as f32 bits) wave w's partial row-max (rides the q3 read).
  __shared__ __align__(16) _Float16 pH[2][PSLOTS];
  // Occupancy pin: 92KB -> 1 block/CU -> (1,1) unlocks the VGPR budget.
  // Doubles as the E^T transpose-staging buffer for backward blocks.
  __shared__ __align__(16) float big[23040];

  const float* up = unary + (size_t)b * (TT * NN);

  // ---- init: buf0 = (fwd: e_START, bwd: filled below), buf1 = 0
  for (int i = tid; i < PSLOTS; i += NT) {
    pH[0][i] = (isF && i == START_IDX) ? (_Float16)1.0f : (_Float16)0.0f;
    pH[1][i] = (_Float16)0.0f;
  }
  if (len < 0) big[23039] = 0.f; // keeps the pin alive
  __syncthreads();               // order aliasing f32 pad stores after fp16 init

  // ---- per-thread output-row table: rows j = 6*gg + r (r<6), plus extra row
  // 192+2w+g for r==6 when g<2.
  int jr[7];
  bool jvalid[7];
#pragma unroll
  for (int r = 0; r < 7; ++r) {
    if (r < 6) { jr[r] = 6 * gg + r; jvalid[r] = true; }
    else       { jr[r] = 192 + 2 * wave + g; jvalid[r] = (g < 2); }
  }

  // ---- fragments: fwd F[j,i]=exp(trans[j,i]) direct coalesced load;
  //      bwd F[j,i]=exp(trans[i,j]) via LDS-staged transpose (big reused).
  //      ALL Er indices are compile-time (rule #20): runtime guards only.
  v2h Er[7][QI / 2];
#pragma unroll
  for (int r = 0; r < 7; ++r)
#pragma unroll
    for (int k = 0; k < QI / 2; ++k) Er[r][k] = v2h{(_Float16)0, (_Float16)0};

  if (isF) {
#pragma unroll
    for (int r = 0; r < 7; ++r) {
      if (!jvalid[r]) continue;
      const int j = jr[r];
      if (c < 7) {
        const float4* t4 = reinterpret_cast<const float4*>(trans + j * NN + c * QI);
#pragma unroll
        for (int k = 0; k < 7; ++k) {
          const float4 tv = t4[k];
          Er[r][2 * k + 0] = v2h{(_Float16)__expf(tv.x), (_Float16)__expf(tv.y)};
          Er[r][2 * k + 1] = v2h{(_Float16)__expf(tv.z), (_Float16)__expf(tv.w)};
        }
      } else {
        const float4 tv = *reinterpret_cast<const float4*>(trans + j * NN + 196);
        Er[r][0] = v2h{(_Float16)__expf(tv.x), (_Float16)__expf(tv.y)};
        Er[r][1] = v2h{(_Float16)__expf(tv.z), (_Float16)__expf(tv.w)};
      }
    }
  } else {
    // staged transpose: round cp stages trans[i = 28cp .. ][all j] into big,
    // then lanes with c==cp read their columns from LDS. Coalesced HBM/L2;
    // Er writes use STATIC m with runtime predication (stays in registers).
    for (int cp = 0; cp < 8; ++cp) {
      const int i0 = 28 * cp;
      const int nrows = (cp < 7) ? 28 : 4; // chunk 7: only i = 196..199 valid
      const int nq = nrows * 50;           // float4s (row = 50 float4)
      __syncthreads(); // previous round's LDS reads complete
      for (int f = tid; f < nq; f += NT) {
        const int row = f / 50, c4 = f - row * 50;
        reinterpret_cast<float4*>(big)[row * 50 + c4] =
            reinterpret_cast<const float4*>(trans + (size_t)(i0 + row) * NN)[c4];
      }
      __syncthreads();
      if (c == cp) {
        const int nm = (cp < 7) ? 14 : 2;
#pragma unroll
        for (int r = 0; r < 7; ++r) {
          if (!jvalid[r]) continue;
          const int j = jr[r];
#pragma unroll
          for (int m = 0; m < 14; ++m) {
            if (m < nm) {
              Er[r][m] = v2h{(_Float16)__expf(big[(2 * m) * NN + j]),
                             (_Float16)__expf(big[(2 * m + 1) * NN + j])};
            }
          }
        }
      }
    }
    __syncthreads();
  }

  // ---- row ownership
  const bool erow = (c < 6) || (c == 6 && g < 2);
  const int jrow = (c < 6) ? (6 * gg + c) : (192 + 2 * wave + g);
  const int wh = (jrow / QI) * CH + (jrow % QI);
  const float* upj = up + jrow;

  // ---- path-specific init
  if (isF) {
    if (tid == 0) *reinterpret_cast<float*>(&pH[0][28]) = 1.0f; // max(p0)=1
    // gold path score
    float gacc = 0.0f;
    for (int t = tid; t < len; t += NT) {
      const int cur = tags[b * TT + t];
      const int prev = (t == 0) ? START_IDX : tags[b * TT + t - 1];
      gacc += trans[cur * NN + prev] + up[(size_t)t * NN + cur];
    }
#pragma unroll
    for (int k = 32; k >= 1; k >>= 1) gacc += __shfl_xor(gacc, k, 64);
    if (lane == 0) big[wave] = gacc;
    __syncthreads();
    if (tid == 0) {
      const int lt = tags[b * TT + len - 1];
      big[16] = big[0] + big[1] + big[2] + big[3] + trans[END_IDX * NN + lt];
    }
  } else {
    // w_{len-1} = exp(u_{len-1}) .* exp(trans[END,:])  (true values, sc=0)
    float wI = 0.f;
    if (erow) {
      wI = __expf(upj[(size_t)(len - 1) * NN] + trans[END_IDX * NN + jrow]);
      pH[0][wh] = (_Float16)wI;
    }
    const float mxI = wave_max_dpp((c < 6) ? wI : 0.f); // lane 63 valid
    if (lane == 63) *reinterpret_cast<float*>(&pH[0][wave * CH + 28]) = mxI;
  }

  // ---- u loader for iteration k's WRITE factor:
  // fwd: u_k (clamped); bwd: u_{len-2-k}, except final iteration -> 0 (factor 1)
  auto uload_k = [&](int k) -> float {
    if (!erow) return 0.f;
    if (isF) {
      const int kk = (k < nsteps) ? k : (nsteps - 1);
      return upj[(size_t)kk * NN];
    }
    if (k >= nsteps - 1) return 0.f;
    return upj[(size_t)(len - 2 - k) * NN];
  };

  float uexpC = erow ? __expf(uload_k(0)) : 0.f;
  float a0r = 0.f, a1r = uload_k(1);
  int isc = 0; // scale: true = 2^isc * stored (EXACT integer accumulation)
  __syncthreads();

  auto STEP = [&](int k, float& con, float& iss) {
    const int rb = k & 1, wb = rb ^ 1;

    const _Float16* pc = &pH[rb][c * CH];
    const uint4 q0 = reinterpret_cast<const uint4*>(pc)[0];
    const uint4 q1 = reinterpret_cast<const uint4*>(pc)[1];
    const uint4 q2 = reinterpret_cast<const uint4*>(pc)[2];
    const uint4 q3 = *reinterpret_cast<const uint4*>(pc + 24); // data + pad

    iss = uload_k(k + 2); // issue early, consume late next step

    // exponent-only normalization: rcpM = 2^-floor(log2 M), isc += e.
    // No transcendental, no rcp, exact scale tracking. M is normal (max of
    // p, p_max kept ~[1, 6e3] by this very normalization).
    const float M = dpp_max8(__int_as_float(q3.z));
    const int eM = (__float_as_int(M) >> 23) - 127;
    const float rcpM = __int_as_float((127 - eM) << 23);
    isc += eM;
    const float f = uexpC * rcpM;

    const unsigned pw[14] = {q0.x, q0.y, q0.z, q0.w, q1.x, q1.y, q1.z, q1.w,
                             q2.x, q2.y, q2.z, q2.w, q3.x, q3.y};
    float a0 = 0.f, a1 = 0.f, a2 = 0.f, a3 = 0.f, a4 = 0.f, a5 = 0.f, a6 = 0.f;
#pragma unroll
    for (int m = 0; m < QI / 2; ++m) {
      const v2h pk = __builtin_bit_cast(v2h, pw[m]);
      a0 = fdot2(Er[0][m], pk, a0);
      a1 = fdot2(Er[1][m], pk, a1);
      a2 = fdot2(Er[2][m], pk, a2);
      a3 = fdot2(Er[3][m], pk, a3);
      a4 = fdot2(Er[4][m], pk, a4);
      a5 = fdot2(Er[5][m], pk, a5);
      a6 = fdot2(Er[6][m], pk, a6);
    }
    const float s0 = dpp_add8(a0);
    const float s1 = dpp_add8(a1);
    const float s2 = dpp_add8(a2);
    const float s3 = dpp_add8(a3);
    const float s4 = dpp_add8(a4);
    const float s5 = dpp_add8(a5);
    const float s6 = dpp_add8(a6);
    float s = s0;
    s = (c == 1) ? s1 : s;
    s = (c == 2) ? s2 : s;
    s = (c == 3) ? s3 : s;
    s = (c == 4) ? s4 : s;
    s = (c == 5) ? s5 : s;
    s = (c == 6) ? s6 : s;

    const float pnew = s * f;
    if (erow) pH[wb][wh] = (_Float16)pnew;
    const float mx = wave_max_dpp((c < 6) ? pnew : 0.f); // lane 63 valid
    if (lane == 63)
      *reinterpret_cast<float*>(&pH[wb][wave * CH + 28]) = mx;

    uexpC = erow ? __expf(con) : 0.f;
    sync_lds();
  };

  int k = 0;
  for (; k + 1 < nsteps; k += 2) {
    STEP(k, a1r, a0r);
    STEP(k + 1, a0r, a1r);
  }
  if (k < nsteps) STEP(k, a1r, a0r);

  // ---- dump half-result: 200 fp32 values + scale (+ gold for fwd)
  const int fb = nsteps & 1;
  const size_t base = (size_t)b * 512 + (isF ? 0 : 256);
  if (tid < NN)
    ws[base + tid] = (float)pH[fb][(tid / QI) * CH + (tid % QI)];
  if (tid == 0) {
    ws[base + 200] = (float)isc;
    if (isF) ws[base + 201] = big[16];
  }
}

// Per-chain merge: Z_b = (scF+scB)*ln2(2) + log(aF . aB); ws2[b] = Z_b - gold_b.
// 8 blocks x 256 threads; 16 threads per chain (coalesced 16-stride reads).
__global__ void crf_merge_kernel(const float* __restrict__ ws,
                                 float* __restrict__ ws2) {
  const int tid = threadIdx.x;
  const int chain = blockIdx.x * 16 + (tid >> 4);
  const int l = tid & 15;
  const float* wf = ws + (size_t)chain * 512;
  float sum = 0.f;
  for (int k = l; k < NN; k += 16) sum += wf[k] * wf[256 + k];
#pragma unroll
  for (int k = 1; k < 16; k <<= 1) sum += __shfl_xor(sum, k, 64);
  if (l == 0) {
    const float Z = (wf[200] + wf[456]) * 0.6931471805599453f + __logf(sum);
    ws2[chain] = Z - wf[201];
  }
}

__global__ void crf_reduce_kernel(const float* __restrict__ ws2,
                                  float* __restrict__ out) {
  const int tid = threadIdx.x; // 128 threads
  float v = ws2[tid];
#pragma unroll
  for (int k = 32; k >= 1; k >>= 1) v += __shfl_xor(v, k, 64);
  __shared__ float s2[2];
  if ((tid & 63) == 0) s2[tid >> 6] = v;
  __syncthreads();
  if (tid == 0) out[0] = (s2[0] + s2[1]) * (1.0f / 128.0f);
}

extern "C" void kernel_launch(void* const* d_in, const int* in_sizes, int n_in,
                              void* d_out, int out_size, void* d_ws, size_t ws_size,
                              hipStream_t stream) {
  const float* unary = (const float*)d_in[0];
  const int* tags = (const int*)d_in[1];
  const int* lengths = (const int*)d_in[2];
  const float* trans = (const float*)d_in[3];
  float* ws = (float*)d_ws;
  float* ws2 = ws + (size_t)BB * 512;
  float* out = (float*)d_out;

  crf_half_kernel<<<2 * BB, NT, 0, stream>>>(unary, tags, lengths, trans, ws);
  crf_merge_kernel<<<8, NT, 0, stream>>>(ws, ws2);
  crf_reduce_kernel<<<1, 128, 0, stream>>>(ws2, out);
}

// Round 18
// 181.300 us; speedup vs baseline: 1.1504x; 1.1504x over previous
//
#include <hip/hip_runtime.h>

typedef _Float16 v2h __attribute__((ext_vector_type(2)));

#define BB 128
#define TT 512
#define NN 200
#define START_IDX 1
#define END_IDX 2

#define NT 256        // 4 waves
#define QI 28         // valid halves per chunk (chunk owner c = lane&7)
#define CH 40         // padded halves per chunk: 80B stride, conflict-free banks
#define PSLOTS (8*CH) // 320

__device__ __forceinline__ float fdot2(v2h a, v2h b, float c) {
  return __builtin_amdgcn_fdot2(a, b, c, false);
}

// LDS-only barrier: does NOT drain vmcnt (global u-prefetch stays in flight).
__device__ __forceinline__ void sync_lds() {
  asm volatile("s_waitcnt lgkmcnt(0)" ::: "memory");
  __builtin_amdgcn_s_barrier();
}

// sum over 8 consecutive lanes; all 8 lanes get the sum
__device__ __forceinline__ float dpp_add8(float x) {
  int v;
  v = __builtin_amdgcn_mov_dpp(__float_as_int(x), 0xB1, 0xF, 0xF, true);
  x += __int_as_float(v);
  v = __builtin_amdgcn_mov_dpp(__float_as_int(x), 0x4E, 0xF, 0xF, true);
  x += __int_as_float(v);
  v = __builtin_amdgcn_mov_dpp(__float_as_int(x), 0x141, 0xF, 0xF, true);
  x += __int_as_float(v);
  return x;
}

// max over 8 consecutive lanes; all 8 lanes get the max
__device__ __forceinline__ float dpp_max8(float x) {
  int v;
  v = __builtin_amdgcn_mov_dpp(__float_as_int(x), 0xB1, 0xF, 0xF, true);
  x = fmaxf(x, __int_as_float(v));
  v = __builtin_amdgcn_mov_dpp(__float_as_int(x), 0x4E, 0xF, 0xF, true);
  x = fmaxf(x, __int_as_float(v));
  v = __builtin_amdgcn_mov_dpp(__float_as_int(x), 0x141, 0xF, 0xF, true);
  x = fmaxf(x, __int_as_float(v));
  return x;
}

// full-wave max (nonneg inputs), pure DPP; result valid in lane 63
__device__ __forceinline__ float wave_max_dpp(float x) {
  int v;
  v = __builtin_amdgcn_mov_dpp(__float_as_int(x), 0xB1, 0xF, 0xF, true);
  x = fmaxf(x, __int_as_float(v));
  v = __builtin_amdgcn_mov_dpp(__float_as_int(x), 0x4E, 0xF, 0xF, true);
  x = fmaxf(x, __int_as_float(v));
  v = __builtin_amdgcn_mov_dpp(__float_as_int(x), 0x141, 0xF, 0xF, true);
  x = fmaxf(x, __int_as_float(v));
  v = __builtin_amdgcn_mov_dpp(__float_as_int(x), 0x140, 0xF, 0xF, true);
  x = fmaxf(x, __int_as_float(v));
  v = __builtin_amdgcn_mov_dpp(__float_as_int(x), 0x142, 0xF, 0xF, true);
  x = fmaxf(x, __int_as_float(v));
  v = __builtin_amdgcn_mov_dpp(__float_as_int(x), 0x143, 0xF, 0xF, true);
  x = fmaxf(x, __int_as_float(v));
  return x;
}

// One block = one half-chain. Block 2b = forward half of chain b (computes
// a_h = M_{h-1}..M_0 a0, h = len/2 steps); block 2b+1 = backward half
// (computes c_h = M_h^T..M_{len-1}^T r, len-h steps, using E^T).
// Z_b = c_h . a_h, merged in crf_merge_kernel.
__global__ __attribute__((amdgpu_flat_work_group_size(NT, NT),
                          amdgpu_waves_per_eu(1, 1)))
void crf_half_kernel(
    const float* __restrict__ unary, const int* __restrict__ tags,
    const int* __restrict__ lengths, const float* __restrict__ trans,
    float* __restrict__ ws) {
  const int bx = blockIdx.x;
  const int b = bx >> 1;
  const bool isF = (bx & 1) == 0;
  const int tid = threadIdx.x;
  const int lane = tid & 63;
  const int wave = tid >> 6;       // 0..3
  const int c = lane & 7;          // i-chunk: i in [28c, 28c+28)
  const int g = (lane >> 3) & 7;   // group within wave
  const int gg = (wave << 3) + g;  // global group id, 0..31
  const int len = lengths[b];
  const int h = len >> 1;
  const int nsteps = isF ? h : (len - h);

  // double-buffered fp16 vector, 80B chunk stride. Pad halves 28..29 of chunk
  // w carry (as f32 bits) wave w's partial row-max (rides the q3 read).
  __shared__ __align__(16) _Float16 pH[2][PSLOTS];
  // Occupancy pin: 92KB -> 1 block/CU -> (1,1) unlocks the VGPR budget.
  __shared__ __align__(16) float big[23040];

  const float* up = unary + (size_t)b * (TT * NN);

  // ---- init: buf0 = (fwd: e_START, bwd: filled below), buf1 = 0
  for (int i = tid; i < PSLOTS; i += NT) {
    pH[0][i] = (isF && i == START_IDX) ? (_Float16)1.0f : (_Float16)0.0f;
    pH[1][i] = (_Float16)0.0f;
  }
  if (len < 0) big[23039] = 0.f; // keeps the pin alive
  __syncthreads();               // order aliasing f32 pad stores after fp16 init

  // ---- fragments: group gg owns OUTPUT rows 6*gg+r (r<6) -> 0..191;
  //      c==6,g<2 extra row 192+2w+g. fwd: F[j,i]=exp(trans[j,i]);
  //      bwd: F[j,i]=exp(trans[i,j]) (E^T, strided one-time load —
  //      measured faster than LDS-staged variants, r16/r17).
  v2h Er[7][QI / 2];
#pragma unroll
  for (int r = 0; r < 7; ++r) {
    int j; bool valid;
    if (r < 6) { j = 6 * gg + r; valid = true; }
    else       { j = 192 + 2 * wave + g; valid = (g < 2); }
    if (valid) {
      if (isF) {
        if (c < 7) {
          const float4* t4 = reinterpret_cast<const float4*>(trans + j * NN + c * QI);
#pragma unroll
          for (int k = 0; k < 7; ++k) {
            const float4 tv = t4[k];
            Er[r][2 * k + 0] = v2h{(_Float16)__expf(tv.x), (_Float16)__expf(tv.y)};
            Er[r][2 * k + 1] = v2h{(_Float16)__expf(tv.z), (_Float16)__expf(tv.w)};
          }
        } else {
          const float4 tv = *reinterpret_cast<const float4*>(trans + j * NN + 196);
          Er[r][0] = v2h{(_Float16)__expf(tv.x), (_Float16)__expf(tv.y)};
          Er[r][1] = v2h{(_Float16)__expf(tv.z), (_Float16)__expf(tv.w)};
#pragma unroll
          for (int k = 2; k < QI / 2; ++k) Er[r][k] = v2h{(_Float16)0, (_Float16)0};
        }
      } else {
        const int nm = (c < 7) ? 14 : 2; // c==7: only inputs 196..199 valid
#pragma unroll
        for (int m = 0; m < QI / 2; ++m) {
          if (m < nm) {
            const int i0 = c * QI + 2 * m;
            Er[r][m] = v2h{(_Float16)__expf(trans[(size_t)i0 * NN + j]),
                           (_Float16)__expf(trans[(size_t)(i0 + 1) * NN + j])};
          } else {
            Er[r][m] = v2h{(_Float16)0, (_Float16)0};
          }
        }
      }
    } else {
#pragma unroll
      for (int k = 0; k < QI / 2; ++k) Er[r][k] = v2h{(_Float16)0, (_Float16)0};
    }
  }

  // ---- row ownership
  const bool erow = (c < 6) || (c == 6 && g < 2);
  const int jrow = (c < 6) ? (6 * gg + c) : (192 + 2 * wave + g);
  const int wh = (jrow / QI) * CH + (jrow % QI);
  const float* upj = up + jrow;

  // ---- path-specific init
  if (isF) {
    if (tid == 0) *reinterpret_cast<float*>(&pH[0][28]) = 1.0f; // max(p0)=1
    // gold path score
    float gacc = 0.0f;
    for (int t = tid; t < len; t += NT) {
      const int cur = tags[b * TT + t];
      const int prev = (t == 0) ? START_IDX : tags[b * TT + t - 1];
      gacc += trans[cur * NN + prev] + up[(size_t)t * NN + cur];
    }
#pragma unroll
    for (int k = 32; k >= 1; k >>= 1) gacc += __shfl_xor(gacc, k, 64);
    if (lane == 0) big[wave] = gacc;
    __syncthreads();
    if (tid == 0) {
      const int lt = tags[b * TT + len - 1];
      big[16] = big[0] + big[1] + big[2] + big[3] + trans[END_IDX * NN + lt];
    }
  } else {
    // w_{len-1} = exp(u_{len-1}) .* exp(trans[END,:])  (true values, sc=0)
    float wI = 0.f;
    if (erow) {
      wI = __expf(upj[(size_t)(len - 1) * NN] + trans[END_IDX * NN + jrow]);
      pH[0][wh] = (_Float16)wI;
    }
    const float mxI = wave_max_dpp((c < 6) ? wI : 0.f); // lane 63 valid
    if (lane == 63) *reinterpret_cast<float*>(&pH[0][wave * CH + 28]) = mxI;
  }

  // ---- u loader for iteration k's WRITE factor:
  // fwd: u_k (clamped); bwd: u_{len-2-k}, except final iteration -> 0 (factor 1)
  auto uload_k = [&](int k) -> float {
    if (!erow) return 0.f;
    if (isF) {
      const int kk = (k < nsteps) ? k : (nsteps - 1);
      return upj[(size_t)kk * NN];
    }
    if (k >= nsteps - 1) return 0.f;
    return upj[(size_t)(len - 2 - k) * NN];
  };

  float uexpC = erow ? __expf(uload_k(0)) : 0.f;
  float a0r = 0.f, a1r = uload_k(1);
  float sc2 = 0.f; // scale (log2): true = 2^sc2 * stored
  __syncthreads();

  auto STEP = [&](int k, float& con, float& iss) {
    const int rb = k & 1, wb = rb ^ 1;

    const _Float16* pc = &pH[rb][c * CH];
    const uint4 q0 = reinterpret_cast<const uint4*>(pc)[0];
    const uint4 q1 = reinterpret_cast<const uint4*>(pc)[1];
    const uint4 q2 = reinterpret_cast<const uint4*>(pc)[2];
    const uint4 q3 = *reinterpret_cast<const uint4*>(pc + 24); // data + pad

    iss = uload_k(k + 2); // issue early, consume late next step

    const float M = dpp_max8(__int_as_float(q3.z));
    const float rcpM = __builtin_amdgcn_rcpf(M);
    sc2 += __log2f(M);
    const float f = uexpC * rcpM;

    const unsigned pw[14] = {q0.x, q0.y, q0.z, q0.w, q1.x, q1.y, q1.z, q1.w,
                             q2.x, q2.y, q2.z, q2.w, q3.x, q3.y};
    float a0 = 0.f, a1 = 0.f, a2 = 0.f, a3 = 0.f, a4 = 0.f, a5 = 0.f, a6 = 0.f;
#pragma unroll
    for (int m = 0; m < QI / 2; ++m) {
      const v2h pk = __builtin_bit_cast(v2h, pw[m]);
      a0 = fdot2(Er[0][m], pk, a0);
      a1 = fdot2(Er[1][m], pk, a1);
      a2 = fdot2(Er[2][m], pk, a2);
      a3 = fdot2(Er[3][m], pk, a3);
      a4 = fdot2(Er[4][m], pk, a4);
      a5 = fdot2(Er[5][m], pk, a5);
      a6 = fdot2(Er[6][m], pk, a6);
    }
    const float s0 = dpp_add8(a0);
    const float s1 = dpp_add8(a1);
    const float s2 = dpp_add8(a2);
    const float s3 = dpp_add8(a3);
    const float s4 = dpp_add8(a4);
    const float s5 = dpp_add8(a5);
    const float s6 = dpp_add8(a6);
    float s = s0;
    s = (c == 1) ? s1 : s;
    s = (c == 2) ? s2 : s;
    s = (c == 3) ? s3 : s;
    s = (c == 4) ? s4 : s;
    s = (c == 5) ? s5 : s;
    s = (c == 6) ? s6 : s;

    const float pnew = s * f;
    if (erow) pH[wb][wh] = (_Float16)pnew;
    const float mx = wave_max_dpp((c < 6) ? pnew : 0.f); // lane 63 valid
    if (lane == 63)
      *reinterpret_cast<float*>(&pH[wb][wave * CH + 28]) = mx;

    uexpC = erow ? __expf(con) : 0.f;
    sync_lds();
  };

  int k = 0;
  for (; k + 1 < nsteps; k += 2) {
    STEP(k, a1r, a0r);
    STEP(k + 1, a0r, a1r);
  }
  if (k < nsteps) STEP(k, a1r, a0r);

  // ---- dump half-result: 200 fp32 values + scale (+ gold for fwd)
  const int fb = nsteps & 1;
  const size_t base = (size_t)b * 512 + (isF ? 0 : 256);
  if (tid < NN)
    ws[base + tid] = (float)pH[fb][(tid / QI) * CH + (tid % QI)];
  if (tid == 0) {
    ws[base + 200] = sc2;
    if (isF) ws[base + 201] = big[16];
  }
}

// Per-chain merge: Z_b = (scF+scB)*ln2 + log(aF . aB); ws2[b] = Z_b - gold_b.
// 8 blocks x 256 threads; 16 threads per chain (coalesced 16-stride reads).
__global__ void crf_merge_kernel(const float* __restrict__ ws,
                                 float* __restrict__ ws2) {
  const int tid = threadIdx.x;
  const int chain = blockIdx.x * 16 + (tid >> 4);
  const int l = tid & 15;
  const float* wf = ws + (size_t)chain * 512;
  float sum = 0.f;
  for (int k = l; k < NN; k += 16) sum += wf[k] * wf[256 + k];
#pragma unroll
  for (int k = 1; k < 16; k <<= 1) sum += __shfl_xor(sum, k, 64);
  if (l == 0) {
    const float Z = (wf[200] + wf[456]) * 0.6931471805599453f + __logf(sum);
    ws2[chain] = Z - wf[201];
  }
}

__global__ void crf_reduce_kernel(const float* __restrict__ ws2,
                                  float* __restrict__ out) {
  const int tid = threadIdx.x; // 128 threads
  float v = ws2[tid];
#pragma unroll
  for (int k = 32; k >= 1; k >>= 1) v += __shfl_xor(v, k, 64);
  __shared__ float s2[2];
  if ((tid & 63) == 0) s2[tid >> 6] = v;
  __syncthreads();
  if (tid == 0) out[0] = (s2[0] + s2[1]) * (1.0f / 128.0f);
}

extern "C" void kernel_launch(void* const* d_in, const int* in_sizes, int n_in,
                              void* d_out, int out_size, void* d_ws, size_t ws_size,
                              hipStream_t stream) {
  const float* unary = (const float*)d_in[0];
  const int* tags = (const int*)d_in[1];
  const int* lengths = (const int*)d_in[2];
  const float* trans = (const float*)d_in[3];
  float* ws = (float*)d_ws;
  float* ws2 = ws + (size_t)BB * 512;
  float* out = (float*)d_out;

  crf_half_kernel<<<2 * BB, NT, 0, stream>>>(unary, tags, lengths, trans, ws);
  crf_merge_kernel<<<8, NT, 0, stream>>>(ws, ws2);
  crf_reduce_kernel<<<1, 128, 0, stream>>>(ws2, out);
}